// Round 5
// baseline (399.683 us; speedup 1.0000x reference)
//
#include <hip/hip_runtime.h>

typedef unsigned short u16;
typedef __attribute__((ext_vector_type(8))) short short8;
typedef __attribute__((ext_vector_type(4))) float f32x4;

#define A_ 4
#define T_ 128
#define B_ 256
#define OBS_ 128
#define H_ 128
#define G_ 384
#define ACT_ 8

__device__ __forceinline__ u16 f2b(float x) {
    unsigned int u = __float_as_uint(x);
    u = (u + 0x7fffu + ((u >> 16) & 1u)) >> 16;
    return (u16)u;
}
__device__ __forceinline__ u16 f2bc(float x) {  // cheap RN (ties up) for hot loop
    return (u16)((__float_as_uint(x) + 0x8000u) >> 16);
}
__device__ __forceinline__ float b2f(u16 h) {
    return __uint_as_float(((unsigned int)h) << 16);
}
__device__ __forceinline__ float fexp2_(float x) { return __builtin_amdgcn_exp2f(x); }
__device__ __forceinline__ float frcp_(float x) { return __builtin_amdgcn_rcpf(x); }
__device__ __forceinline__ float sigmoidf_(float x) {
    return frcp_(1.0f + fexp2_(-1.4426950408889634f * x));
}
__device__ __forceinline__ float tanhf_(float x) {
    return 1.0f - 2.0f * frcp_(1.0f + fexp2_(2.8853900817779268f * x));
}
__device__ __forceinline__ f32x4 mfma16(short8 a, short8 b, f32x4 c) {
    return __builtin_amdgcn_mfma_f32_16x16x32_bf16(a, b, c, 0, 0, 0);
}

// Barrier that waits ONLY on LDS ops (lgkmcnt(0)), not vmcnt — avoids the
// __syncthreads per-step drain of global stores + prefetch loads (m97 stall).
// 0xC07F: vmcnt=63, expcnt=7, lgkmcnt=0 (encoding valid for 4- and 6-bit lgkm).
__device__ __forceinline__ void bar_lds() {
    __asm__ volatile("" ::: "memory");
    __builtin_amdgcn_s_waitcnt(0xC07F);
    __builtin_amdgcn_s_barrier();
    __asm__ volatile("" ::: "memory");
}

// ---------------- K0: weight transpose/convert + std output ----------------
__global__ void k_prep(const float* __restrict__ We, const float* __restrict__ Wi,
                       const float* __restrict__ Wh, const float* __restrict__ Wa1,
                       const float* __restrict__ Wc1, const float* __restrict__ Wa2,
                       const float* __restrict__ Wc2, const float* __restrict__ log_std,
                       u16* __restrict__ weT, u16* __restrict__ wiT, u16* __restrict__ whT,
                       u16* __restrict__ wa1T, u16* __restrict__ wc1T, u16* __restrict__ h2T,
                       float* __restrict__ std_out) {
    const int PER_A = 149504;
    int idx = blockIdx.x * 256 + threadIdx.x;
    const int total = 4 * PER_A;
    if (idx < total) {
        int a = idx / PER_A;
        int i = idx % PER_A;
        if (i < 16384) {
            int h = i >> 7, o = i & 127;
            weT[a * 16384 + i] = f2b(We[a * 16384 + o * 128 + h]);
        } else if (i < 16384 + 49152) {
            int j = i - 16384; int g = j >> 7, k = j & 127;
            wiT[a * 49152 + j] = f2b(Wi[a * 49152 + k * 384 + g]);
        } else if (i < 16384 + 2 * 49152) {
            int j = i - 16384 - 49152; int g = j >> 7, k = j & 127;
            whT[a * 49152 + j] = f2b(Wh[a * 49152 + k * 384 + g]);
        } else if (i < 2 * 16384 + 2 * 49152) {
            int j = i - 16384 - 2 * 49152; int h2 = j >> 7, k = j & 127;
            wa1T[a * 16384 + j] = f2b(Wa1[a * 16384 + k * 128 + h2]);
        } else if (i < 3 * 16384 + 2 * 49152) {
            int j = i - 2 * 16384 - 2 * 49152; int h2 = j >> 7, k = j & 127;
            wc1T[a * 16384 + j] = f2b(Wc1[a * 16384 + k * 128 + h2]);
        } else {
            int j = i - 3 * 16384 - 2 * 49152; int row = j >> 7, k = j & 127;
            float v = 0.f;
            if (row < 8) v = Wa2[a * 1024 + k * 8 + row];
            else if (row == 8) v = Wc2[a * 128 + k];
            h2T[a * 2048 + j] = f2b(v);
        }
    } else if (idx < total + 32) {
        int i = idx - total;
        std_out[i] = __expf(log_std[i]);
    }
}

// ---------------- K1: fused emb/xi, weight-stationary ----------------------
__global__ __launch_bounds__(512) void k_embed_xi(
    const float* __restrict__ obs, const float* __restrict__ be, const float* __restrict__ bi,
    const u16* __restrict__ weT, const u16* __restrict__ wiT, u16* __restrict__ xi_ws) {
    __shared__ __align__(16) u16 obsl[16][136];
    __shared__ __align__(16) u16 elds[16][136];
    const int a = blockIdx.y, t = blockIdx.x;
    const int wid = threadIdx.x >> 6, lane = threadIdx.x & 63;
    const int m = lane & 15, quad = lane >> 4;
    const int srow = threadIdx.x >> 5, schunk = threadIdx.x & 31;

    short8 we[4], wi[3][4];
    {
        const u16* p = weT + a * 16384 + (wid * 16 + m) * 128 + quad * 8;
#pragma unroll
        for (int ks = 0; ks < 4; ++ks) we[ks] = *(const short8*)(p + ks * 32);
#pragma unroll
        for (int g = 0; g < 3; ++g) {
            const u16* q = wiT + a * 49152 + (g * 128 + wid * 16 + m) * 128 + quad * 8;
#pragma unroll
            for (int ks = 0; ks < 4; ++ks) wi[g][ks] = *(const short8*)(q + ks * 32);
        }
    }
    const float bee = be[a * H_ + wid * 16 + m];
    float big[3];
#pragma unroll
    for (int g = 0; g < 3; ++g) big[g] = bi[a * G_ + g * 128 + wid * 16 + m];

    const float* obsrow = obs + ((size_t)(a * T_ + t) * B_ + srow) * OBS_ + schunk * 4;
    float4 pf = *(const float4*)(obsrow);
    ushort4* xi4 = (ushort4*)xi_ws;

    for (int it = 0; it < 16; ++it) {
        ushort4 ob;
        ob.x = f2b(pf.x); ob.y = f2b(pf.y); ob.z = f2b(pf.z); ob.w = f2b(pf.w);
        *(ushort4*)&obsl[srow][schunk * 4] = ob;
        bar_lds();
        if (it + 1 < 16) pf = *(const float4*)(obsrow + (size_t)(it + 1) * 2048);

        short8 af[4];
#pragma unroll
        for (int ks = 0; ks < 4; ++ks)
            af[ks] = *(const short8*)&obsl[m][ks * 32 + quad * 8];
        f32x4 acc = f32x4{0.f, 0.f, 0.f, 0.f};
#pragma unroll
        for (int ks = 0; ks < 4; ++ks) acc = mfma16(af[ks], we[ks], acc);
#pragma unroll
        for (int r = 0; r < 4; ++r)
            elds[quad * 4 + r][wid * 16 + m] = f2b(tanhf_(acc[r] + bee));
        bar_lds();

        short8 ef[4];
#pragma unroll
        for (int ks = 0; ks < 4; ++ks)
            ef[ks] = *(const short8*)&elds[m][ks * 32 + quad * 8];
        f32x4 xa[3];
#pragma unroll
        for (int g = 0; g < 3; ++g) xa[g] = f32x4{0.f, 0.f, 0.f, 0.f};
#pragma unroll
        for (int ks = 0; ks < 4; ++ks)
#pragma unroll
            for (int g = 0; g < 3; ++g) xa[g] = mfma16(ef[ks], wi[g][ks], xa[g]);

        const size_t base = ((size_t)(a * 16 + it) * T_ + t) * 1536;
#pragma unroll
        for (int g = 0; g < 3; ++g) {
            ushort4 pk;
            pk.x = f2b(xa[g][0] + big[g]);
            pk.y = f2b(xa[g][1] + big[g]);
            pk.z = f2b(xa[g][2] + big[g]);
            pk.w = f2b(xa[g][3] + big[g]);
            xi4[base + (size_t)(wid * 3 + g) * 64 + lane] = pk;
        }
    }
}

// ---------------- K2: GRU scan, 8 waves, lgkm-only barrier, prefetch-2 -----
// grid (16,4) x 512 thr. Wave wid owns h-cols [16*wid,16*wid+16) and r,z,n
// gate tiles (12 MFMA/step). h fp32 in regs (C-layout); bf16 copy through
// double-buffered LDS as MFMA A-operand. One lgkm-only barrier per step;
// ys stores / xi+done prefetch (distance 2) drain lazily via vmcnt(N).
__global__ __launch_bounds__(512) void k_scan(
    const float* __restrict__ hstate, const u16* __restrict__ xi_ws,
    const u16* __restrict__ whT, const float* __restrict__ bhn,
    const int* __restrict__ done, u16* __restrict__ ys_ws, float* __restrict__ hT_out) {
    __shared__ __align__(16) u16 hlds[2][16][136];
    const int a = blockIdx.y, btile = blockIdx.x;
    const int wid = threadIdx.x >> 6, lane = threadIdx.x & 63;
    const int m = lane & 15, quad = lane >> 4;
    const int b0 = btile * 16;
    const int col = 16 * wid + m;

    short8 wh[3][4];
    const u16* whTa = whT + a * 49152;
#pragma unroll
    for (int g = 0; g < 3; ++g) {
        const u16* p = whTa + (g * 128 + col) * 128 + quad * 8;
#pragma unroll
        for (int ks = 0; ks < 4; ++ks) wh[g][ks] = *(const short8*)(p + ks * 32);
    }

    float hm[4]; u16 hb[4];
#pragma unroll
    for (int r = 0; r < 4; ++r) {
        float v = hstate[((size_t)a * B_ + b0 + quad * 4 + r) * H_ + col];
        hm[r] = v; hb[r] = f2b(v);
    }
    const float bh = bhn[a * H_ + col];

    const ushort4* xi4 = (const ushort4*)xi_ws;
    const size_t xibase = ((size_t)(a * 16 + btile) * T_) * 1536 + wid * 192 + lane;
    const int* dbase = done + (size_t)a * T_ * B_ + b0 + quad * 4;

    // prefetch distance 2
    ushort4 px[2][3];
    int dn[2][4];
#pragma unroll
    for (int s = 0; s < 2; ++s) {
        const size_t xb = xibase + (size_t)s * 1536;
        px[s][0] = xi4[xb]; px[s][1] = xi4[xb + 64]; px[s][2] = xi4[xb + 128];
        const int* dp = dbase + (size_t)s * B_;
#pragma unroll
        for (int r = 0; r < 4; ++r) dn[s][r] = dp[r];
    }

    for (int t = 0; t < T_; ++t) {
        const int cur = t & 1;
        u16 (*hl)[136] = hlds[cur];
#pragma unroll
        for (int r = 0; r < 4; ++r) {
            if (dn[cur][r]) { hm[r] = 0.f; hb[r] = 0; }
            hl[quad * 4 + r][col] = hb[r];
        }
        bar_lds();

        float xr[4], xz[4], xn[4];
        xr[0] = b2f(px[cur][0].x); xr[1] = b2f(px[cur][0].y);
        xr[2] = b2f(px[cur][0].z); xr[3] = b2f(px[cur][0].w);
        xz[0] = b2f(px[cur][1].x); xz[1] = b2f(px[cur][1].y);
        xz[2] = b2f(px[cur][1].z); xz[3] = b2f(px[cur][1].w);
        xn[0] = b2f(px[cur][2].x); xn[1] = b2f(px[cur][2].y);
        xn[2] = b2f(px[cur][2].z); xn[3] = b2f(px[cur][2].w);
        if (t + 2 < T_) {
            const size_t nx = xibase + (size_t)(t + 2) * 1536;
            px[cur][0] = xi4[nx]; px[cur][1] = xi4[nx + 64]; px[cur][2] = xi4[nx + 128];
            const int* dp = dbase + (size_t)(t + 2) * B_;
#pragma unroll
            for (int r = 0; r < 4; ++r) dn[cur][r] = dp[r];
        }

        short8 af[4];
#pragma unroll
        for (int ks = 0; ks < 4; ++ks)
            af[ks] = *(const short8*)&hl[m][ks * 32 + quad * 8];

        f32x4 ar = f32x4{0.f, 0.f, 0.f, 0.f};
        f32x4 az = f32x4{0.f, 0.f, 0.f, 0.f};
        f32x4 an = f32x4{0.f, 0.f, 0.f, 0.f};
#pragma unroll
        for (int ks = 0; ks < 4; ++ks) {
            ar = mfma16(af[ks], wh[0][ks], ar);
            az = mfma16(af[ks], wh[1][ks], az);
            an = mfma16(af[ks], wh[2][ks], an);
        }

#pragma unroll
        for (int r = 0; r < 4; ++r) {
            const float rg = sigmoidf_(xr[r] + ar[r]);
            const float zg = sigmoidf_(xz[r] + az[r]);
            const float ng = tanhf_(fmaf(rg, an[r] + bh, xn[r]));
            const float hn2 = fmaf(zg, hm[r] - ng, ng);
            hm[r] = hn2;
            hb[r] = f2bc(hn2);
            ys_ws[(((size_t)a * T_ + t) * B_ + b0 + quad * 4 + r) * H_ + col] = hb[r];
        }
    }
#pragma unroll
    for (int r = 0; r < 4; ++r)
        hT_out[((size_t)a * B_ + b0 + quad * 4 + r) * H_ + col] = hm[r];
}

// ---------------- K3: actor/critic heads, weight-stationary ----------------
__global__ __launch_bounds__(512) void k_heads(
    const u16* __restrict__ ys_ws, const u16* __restrict__ wa1T, const u16* __restrict__ wc1T,
    const u16* __restrict__ h2T, const float* __restrict__ ba1, const float* __restrict__ bc1,
    const float* __restrict__ ba2, const float* __restrict__ bc2,
    float* __restrict__ mean_out, float* __restrict__ val_out) {
    __shared__ __align__(16) u16 ysl[16][136];
    __shared__ __align__(16) u16 al[2][16][136];
    const int a = blockIdx.y;
    const int wid = threadIdx.x >> 6, lane = threadIdx.x & 63;
    const int m = lane & 15, quad = lane >> 4;
    const int srow = threadIdx.x >> 5, schunk = threadIdx.x & 31;

    short8 wa[4], wc[4], h2f[4];
    {
        const u16* pa = wa1T + a * 16384 + (wid * 16 + m) * 128 + quad * 8;
        const u16* pc = wc1T + a * 16384 + (wid * 16 + m) * 128 + quad * 8;
        const u16* ph = h2T + a * 2048 + m * 128 + quad * 8;
#pragma unroll
        for (int ks = 0; ks < 4; ++ks) {
            wa[ks] = *(const short8*)(pa + ks * 32);
            wc[ks] = *(const short8*)(pc + ks * 32);
            h2f[ks] = *(const short8*)(ph + ks * 32);
        }
    }
    const float fa = ba1[a * 128 + wid * 16 + m];
    const float fc = bc1[a * 128 + wid * 16 + m];

    const u16* ysbase = ys_ws + ((size_t)a * 32768 + (size_t)blockIdx.x * 256 + srow) * 128 + schunk * 4;
    ushort4 pf = *(const ushort4*)(ysbase);

    for (int it = 0; it < 16; ++it) {
        *(ushort4*)&ysl[srow][schunk * 4] = pf;
        bar_lds();
        if (it + 1 < 16) pf = *(const ushort4*)(ysbase + (size_t)(it + 1) * 2048);

        short8 yf[4];
#pragma unroll
        for (int ks = 0; ks < 4; ++ks)
            yf[ks] = *(const short8*)&ysl[m][ks * 32 + quad * 8];
        f32x4 aa = f32x4{0.f, 0.f, 0.f, 0.f};
        f32x4 ac = f32x4{0.f, 0.f, 0.f, 0.f};
#pragma unroll
        for (int ks = 0; ks < 4; ++ks) {
            aa = mfma16(yf[ks], wa[ks], aa);
            ac = mfma16(yf[ks], wc[ks], ac);
        }
#pragma unroll
        for (int r = 0; r < 4; ++r) {
            al[0][quad * 4 + r][wid * 16 + m] = f2b(tanhf_(aa[r] + fa));
            al[1][quad * 4 + r][wid * 16 + m] = f2b(tanhf_(ac[r] + fc));
        }
        bar_lds();

        if (wid < 2) {
            short8 tf[4];
#pragma unroll
            for (int ks = 0; ks < 4; ++ks)
                tf[ks] = *(const short8*)&al[wid][m][ks * 32 + quad * 8];
            f32x4 tacc = f32x4{0.f, 0.f, 0.f, 0.f};
#pragma unroll
            for (int ks = 0; ks < 4; ++ks) tacc = mfma16(tf[ks], h2f[ks], tacc);
            const size_t R0 = (size_t)a * 32768 + (size_t)(blockIdx.x * 16 + it) * 16;
            if (wid == 0) {
                if (m < 8) {
                    const float bb = ba2[a * 8 + m];
#pragma unroll
                    for (int r = 0; r < 4; ++r)
                        mean_out[(R0 + quad * 4 + r) * 8 + m] = tacc[r] + bb;
                }
            } else {
                if (m == 8) {
                    const float bb = bc2[a];
#pragma unroll
                    for (int r = 0; r < 4; ++r)
                        val_out[R0 + quad * 4 + r] = tacc[r] + bb;
                }
            }
        }
    }
}

extern "C" void kernel_launch(void* const* d_in, const int* in_sizes, int n_in,
                              void* d_out, int out_size, void* d_ws, size_t ws_size,
                              hipStream_t stream) {
    const float* hstate = (const float*)d_in[0];
    const float* obs = (const float*)d_in[1];
    const float* We = (const float*)d_in[3];
    const float* be = (const float*)d_in[4];
    const float* Wi = (const float*)d_in[5];
    const float* bi = (const float*)d_in[6];
    const float* Wh = (const float*)d_in[7];
    const float* bhn = (const float*)d_in[8];
    const float* Wa1 = (const float*)d_in[9];
    const float* ba1 = (const float*)d_in[10];
    const float* Wa2 = (const float*)d_in[11];
    const float* ba2 = (const float*)d_in[12];
    const float* log_std = (const float*)d_in[13];
    const float* Wc1 = (const float*)d_in[14];
    const float* bc1 = (const float*)d_in[15];
    const float* Wc2 = (const float*)d_in[16];
    const float* bc2 = (const float*)d_in[17];
    const int* done = (const int*)d_in[18];

    float* out = (float*)d_out;
    float* hT_out = out;                    // (4,256,128)
    float* mean_out = out + 131072;         // (4,128,256,8)
    float* std_out = out + 1179648;         // (4,8)
    float* val_out = out + 1179680;         // (4,128,256)

    u16* ws = (u16*)d_ws;
    u16* xi = ws;
    u16* ys = xi + 50331648;
    u16* weT = ys + 16777216;
    u16* wiT = weT + 65536;
    u16* whT = wiT + 196608;
    u16* wa1T = whT + 196608;
    u16* wc1T = wa1T + 65536;
    u16* h2T = wc1T + 65536;

    hipLaunchKernelGGL(k_prep, dim3(2337), dim3(256), 0, stream,
                       We, Wi, Wh, Wa1, Wc1, Wa2, Wc2, log_std,
                       weT, wiT, whT, wa1T, wc1T, h2T, std_out);
    hipLaunchKernelGGL(k_embed_xi, dim3(128, 4), dim3(512), 0, stream,
                       obs, be, bi, weT, wiT, xi);
    hipLaunchKernelGGL(k_scan, dim3(16, 4), dim3(512), 0, stream,
                       hstate, xi, whT, bhn, done, ys, hT_out);
    hipLaunchKernelGGL(k_heads, dim3(128, 4), dim3(512), 0, stream,
                       ys, wa1T, wc1T, h2T, ba1, bc1, ba2, bc2, mean_out, val_out);
}

// Round 6
// 308.183 us; speedup vs baseline: 1.2969x; 1.2969x over previous
//
#include <hip/hip_runtime.h>

typedef unsigned short u16;
typedef __attribute__((ext_vector_type(8))) short short8;
typedef __attribute__((ext_vector_type(4))) float f32x4;

#define A_ 4
#define T_ 128
#define B_ 256
#define OBS_ 128
#define H_ 128
#define G_ 384
#define ACT_ 8

__device__ __forceinline__ u16 f2b(float x) {
    unsigned int u = __float_as_uint(x);
    u = (u + 0x7fffu + ((u >> 16) & 1u)) >> 16;
    return (u16)u;
}
__device__ __forceinline__ u16 f2bc(float x) {  // cheap RN (ties up) for hot loop
    return (u16)((__float_as_uint(x) + 0x8000u) >> 16);
}
__device__ __forceinline__ float b2f(u16 h) {
    return __uint_as_float(((unsigned int)h) << 16);
}
__device__ __forceinline__ float fexp2_(float x) { return __builtin_amdgcn_exp2f(x); }
__device__ __forceinline__ float frcp_(float x) { return __builtin_amdgcn_rcpf(x); }
__device__ __forceinline__ float sigmoidf_(float x) {
    return frcp_(1.0f + fexp2_(-1.4426950408889634f * x));
}
__device__ __forceinline__ float tanhf_(float x) {
    return 1.0f - 2.0f * frcp_(1.0f + fexp2_(2.8853900817779268f * x));
}
__device__ __forceinline__ f32x4 mfma16(short8 a, short8 b, f32x4 c) {
    return __builtin_amdgcn_mfma_f32_16x16x32_bf16(a, b, c, 0, 0, 0);
}

// Barrier that waits ONLY on LDS ops (lgkmcnt(0)), not vmcnt — avoids the
// __syncthreads per-step drain of global stores + prefetch loads.
// 0xC07F: vmcnt=63, expcnt=7, lgkmcnt=0.
__device__ __forceinline__ void bar_lds() {
    __asm__ volatile("" ::: "memory");
    __builtin_amdgcn_s_waitcnt(0xC07F);
    __builtin_amdgcn_s_barrier();
    __asm__ volatile("" ::: "memory");
}

// ---------------- K0: weight transpose/convert + std output ----------------
__global__ void k_prep(const float* __restrict__ We, const float* __restrict__ Wi,
                       const float* __restrict__ Wh, const float* __restrict__ Wa1,
                       const float* __restrict__ Wc1, const float* __restrict__ Wa2,
                       const float* __restrict__ Wc2, const float* __restrict__ log_std,
                       u16* __restrict__ weT, u16* __restrict__ wiT, u16* __restrict__ whT,
                       u16* __restrict__ wa1T, u16* __restrict__ wc1T, u16* __restrict__ h2T,
                       float* __restrict__ std_out) {
    const int PER_A = 149504;
    int idx = blockIdx.x * 256 + threadIdx.x;
    const int total = 4 * PER_A;
    if (idx < total) {
        int a = idx / PER_A;
        int i = idx % PER_A;
        if (i < 16384) {
            int h = i >> 7, o = i & 127;
            weT[a * 16384 + i] = f2b(We[a * 16384 + o * 128 + h]);
        } else if (i < 16384 + 49152) {
            int j = i - 16384; int g = j >> 7, k = j & 127;
            wiT[a * 49152 + j] = f2b(Wi[a * 49152 + k * 384 + g]);
        } else if (i < 16384 + 2 * 49152) {
            int j = i - 16384 - 49152; int g = j >> 7, k = j & 127;
            whT[a * 49152 + j] = f2b(Wh[a * 49152 + k * 384 + g]);
        } else if (i < 2 * 16384 + 2 * 49152) {
            int j = i - 16384 - 2 * 49152; int h2 = j >> 7, k = j & 127;
            wa1T[a * 16384 + j] = f2b(Wa1[a * 16384 + k * 128 + h2]);
        } else if (i < 3 * 16384 + 2 * 49152) {
            int j = i - 2 * 16384 - 2 * 49152; int h2 = j >> 7, k = j & 127;
            wc1T[a * 16384 + j] = f2b(Wc1[a * 16384 + k * 128 + h2]);
        } else {
            int j = i - 3 * 16384 - 2 * 49152; int row = j >> 7, k = j & 127;
            float v = 0.f;
            if (row < 8) v = Wa2[a * 1024 + k * 8 + row];
            else if (row == 8) v = Wc2[a * 128 + k];
            h2T[a * 2048 + j] = f2b(v);
        }
    } else if (idx < total + 32) {
        int i = idx - total;
        std_out[i] = __expf(log_std[i]);
    }
}

// ---------------- K1: fused emb/xi, weight-stationary ----------------------
__global__ __launch_bounds__(512) void k_embed_xi(
    const float* __restrict__ obs, const float* __restrict__ be, const float* __restrict__ bi,
    const u16* __restrict__ weT, const u16* __restrict__ wiT, u16* __restrict__ xi_ws) {
    __shared__ __align__(16) u16 obsl[16][136];
    __shared__ __align__(16) u16 elds[16][136];
    const int a = blockIdx.y, t = blockIdx.x;
    const int wid = threadIdx.x >> 6, lane = threadIdx.x & 63;
    const int m = lane & 15, quad = lane >> 4;
    const int srow = threadIdx.x >> 5, schunk = threadIdx.x & 31;

    short8 we[4], wi[3][4];
    {
        const u16* p = weT + a * 16384 + (wid * 16 + m) * 128 + quad * 8;
#pragma unroll
        for (int ks = 0; ks < 4; ++ks) we[ks] = *(const short8*)(p + ks * 32);
#pragma unroll
        for (int g = 0; g < 3; ++g) {
            const u16* q = wiT + a * 49152 + (g * 128 + wid * 16 + m) * 128 + quad * 8;
#pragma unroll
            for (int ks = 0; ks < 4; ++ks) wi[g][ks] = *(const short8*)(q + ks * 32);
        }
    }
    const float bee = be[a * H_ + wid * 16 + m];
    float big[3];
#pragma unroll
    for (int g = 0; g < 3; ++g) big[g] = bi[a * G_ + g * 128 + wid * 16 + m];

    const float* obsrow = obs + ((size_t)(a * T_ + t) * B_ + srow) * OBS_ + schunk * 4;
    float4 pf = *(const float4*)(obsrow);
    ushort4* xi4 = (ushort4*)xi_ws;

    for (int it = 0; it < 16; ++it) {
        ushort4 ob;
        ob.x = f2b(pf.x); ob.y = f2b(pf.y); ob.z = f2b(pf.z); ob.w = f2b(pf.w);
        *(ushort4*)&obsl[srow][schunk * 4] = ob;
        bar_lds();
        if (it + 1 < 16) pf = *(const float4*)(obsrow + (size_t)(it + 1) * 2048);

        short8 af[4];
#pragma unroll
        for (int ks = 0; ks < 4; ++ks)
            af[ks] = *(const short8*)&obsl[m][ks * 32 + quad * 8];
        f32x4 acc = f32x4{0.f, 0.f, 0.f, 0.f};
#pragma unroll
        for (int ks = 0; ks < 4; ++ks) acc = mfma16(af[ks], we[ks], acc);
#pragma unroll
        for (int r = 0; r < 4; ++r)
            elds[quad * 4 + r][wid * 16 + m] = f2b(tanhf_(acc[r] + bee));
        bar_lds();

        short8 ef[4];
#pragma unroll
        for (int ks = 0; ks < 4; ++ks)
            ef[ks] = *(const short8*)&elds[m][ks * 32 + quad * 8];
        f32x4 xa[3];
#pragma unroll
        for (int g = 0; g < 3; ++g) xa[g] = f32x4{0.f, 0.f, 0.f, 0.f};
#pragma unroll
        for (int ks = 0; ks < 4; ++ks)
#pragma unroll
            for (int g = 0; g < 3; ++g) xa[g] = mfma16(ef[ks], wi[g][ks], xa[g]);

        const size_t base = ((size_t)(a * 16 + it) * T_ + t) * 1536;
#pragma unroll
        for (int g = 0; g < 3; ++g) {
            ushort4 pk;
            pk.x = f2b(xa[g][0] + big[g]);
            pk.y = f2b(xa[g][1] + big[g]);
            pk.z = f2b(xa[g][2] + big[g]);
            pk.w = f2b(xa[g][3] + big[g]);
            xi4[base + (size_t)(wid * 3 + g) * 64 + lane] = pk;
        }
    }
}

// ---------------- K2: GRU scan, 8 waves, lgkm-only barrier -----------------
// grid (16,4) x 512 thr. t-loop unrolled by 2 with STATIC register sets
// (pxA/dnA -> hlds[0] even steps, pxB/dnB -> hlds[1] odd steps) so no local
// array is dynamically indexed (r5's PromoteAlloca-to-LDS trap). Prefetch
// distance 2; ys stores & prefetch loads drain lazily (no vmcnt at barrier).
__global__ __launch_bounds__(512) void k_scan(
    const float* __restrict__ hstate, const u16* __restrict__ xi_ws,
    const u16* __restrict__ whT, const float* __restrict__ bhn,
    const int* __restrict__ done, u16* __restrict__ ys_ws, float* __restrict__ hT_out) {
    __shared__ __align__(16) u16 hlds[2][16][136];
    const int a = blockIdx.y, btile = blockIdx.x;
    const int wid = threadIdx.x >> 6, lane = threadIdx.x & 63;
    const int m = lane & 15, quad = lane >> 4;
    const int b0 = btile * 16;
    const int col = 16 * wid + m;

    short8 wh[3][4];
    const u16* whTa = whT + a * 49152;
#pragma unroll
    for (int g = 0; g < 3; ++g) {
        const u16* p = whTa + (g * 128 + col) * 128 + quad * 8;
#pragma unroll
        for (int ks = 0; ks < 4; ++ks) wh[g][ks] = *(const short8*)(p + ks * 32);
    }

    float hm[4]; u16 hb[4];
#pragma unroll
    for (int r = 0; r < 4; ++r) {
        float v = hstate[((size_t)a * B_ + b0 + quad * 4 + r) * H_ + col];
        hm[r] = v; hb[r] = f2b(v);
    }
    const float bh = bhn[a * H_ + col];

    const ushort4* xi4 = (const ushort4*)xi_ws;
    const size_t xibase = ((size_t)(a * 16 + btile) * T_) * 1536 + wid * 192 + lane;
    const int* dbase = done + (size_t)a * T_ * B_ + b0 + quad * 4;

    // prefetch distance 2: A = even steps, B = odd steps (all scalars)
    ushort4 pA0 = xi4[xibase], pA1 = xi4[xibase + 64], pA2 = xi4[xibase + 128];
    int dA0 = dbase[0], dA1 = dbase[1], dA2 = dbase[2], dA3 = dbase[3];
    ushort4 pB0 = xi4[xibase + 1536], pB1 = xi4[xibase + 1536 + 64], pB2 = xi4[xibase + 1536 + 128];
    int dB0 = dbase[B_], dB1 = dbase[B_ + 1], dB2 = dbase[B_ + 2], dB3 = dbase[B_ + 3];

#define SCAN_STEP(BUF, P0, P1, P2, D0, D1, D2, D3, TT)                          \
    {                                                                           \
        u16 (*hl)[136] = hlds[BUF];                                             \
        if (D0) { hm[0] = 0.f; hb[0] = 0; }                                     \
        if (D1) { hm[1] = 0.f; hb[1] = 0; }                                     \
        if (D2) { hm[2] = 0.f; hb[2] = 0; }                                     \
        if (D3) { hm[3] = 0.f; hb[3] = 0; }                                     \
        hl[quad * 4 + 0][col] = hb[0];                                          \
        hl[quad * 4 + 1][col] = hb[1];                                          \
        hl[quad * 4 + 2][col] = hb[2];                                          \
        hl[quad * 4 + 3][col] = hb[3];                                          \
        bar_lds();                                                              \
        float xr[4], xz[4], xn[4];                                              \
        xr[0] = b2f(P0.x); xr[1] = b2f(P0.y); xr[2] = b2f(P0.z); xr[3] = b2f(P0.w); \
        xz[0] = b2f(P1.x); xz[1] = b2f(P1.y); xz[2] = b2f(P1.z); xz[3] = b2f(P1.w); \
        xn[0] = b2f(P2.x); xn[1] = b2f(P2.y); xn[2] = b2f(P2.z); xn[3] = b2f(P2.w); \
        if ((TT) + 2 < T_) {                                                    \
            const size_t nx = xibase + (size_t)((TT) + 2) * 1536;               \
            P0 = xi4[nx]; P1 = xi4[nx + 64]; P2 = xi4[nx + 128];                \
            const int* dp = dbase + (size_t)((TT) + 2) * B_;                    \
            D0 = dp[0]; D1 = dp[1]; D2 = dp[2]; D3 = dp[3];                     \
        }                                                                       \
        short8 af[4];                                                           \
        _Pragma("unroll")                                                       \
        for (int ks = 0; ks < 4; ++ks)                                          \
            af[ks] = *(const short8*)&hl[m][ks * 32 + quad * 8];                \
        f32x4 ar = f32x4{0.f, 0.f, 0.f, 0.f};                                   \
        f32x4 az = f32x4{0.f, 0.f, 0.f, 0.f};                                   \
        f32x4 an = f32x4{0.f, 0.f, 0.f, 0.f};                                   \
        _Pragma("unroll")                                                       \
        for (int ks = 0; ks < 4; ++ks) {                                        \
            ar = mfma16(af[ks], wh[0][ks], ar);                                 \
            az = mfma16(af[ks], wh[1][ks], az);                                 \
            an = mfma16(af[ks], wh[2][ks], an);                                 \
        }                                                                       \
        _Pragma("unroll")                                                       \
        for (int r = 0; r < 4; ++r) {                                           \
            const float rg = sigmoidf_(xr[r] + ar[r]);                          \
            const float zg = sigmoidf_(xz[r] + az[r]);                          \
            const float ng = tanhf_(fmaf(rg, an[r] + bh, xn[r]));               \
            const float hn2 = fmaf(zg, hm[r] - ng, ng);                         \
            hm[r] = hn2;                                                        \
            hb[r] = f2bc(hn2);                                                  \
            ys_ws[(((size_t)a * T_ + (TT)) * B_ + b0 + quad * 4 + r) * H_ + col] = hb[r]; \
        }                                                                       \
    }

    for (int t = 0; t < T_; t += 2) {
        SCAN_STEP(0, pA0, pA1, pA2, dA0, dA1, dA2, dA3, t)
        SCAN_STEP(1, pB0, pB1, pB2, dB0, dB1, dB2, dB3, t + 1)
    }
#undef SCAN_STEP

#pragma unroll
    for (int r = 0; r < 4; ++r)
        hT_out[((size_t)a * B_ + b0 + quad * 4 + r) * H_ + col] = hm[r];
}

// ---------------- K3: actor/critic heads, weight-stationary ----------------
__global__ __launch_bounds__(512) void k_heads(
    const u16* __restrict__ ys_ws, const u16* __restrict__ wa1T, const u16* __restrict__ wc1T,
    const u16* __restrict__ h2T, const float* __restrict__ ba1, const float* __restrict__ bc1,
    const float* __restrict__ ba2, const float* __restrict__ bc2,
    float* __restrict__ mean_out, float* __restrict__ val_out) {
    __shared__ __align__(16) u16 ysl[16][136];
    __shared__ __align__(16) u16 al[2][16][136];
    const int a = blockIdx.y;
    const int wid = threadIdx.x >> 6, lane = threadIdx.x & 63;
    const int m = lane & 15, quad = lane >> 4;
    const int srow = threadIdx.x >> 5, schunk = threadIdx.x & 31;

    short8 wa[4], wc[4], h2f[4];
    {
        const u16* pa = wa1T + a * 16384 + (wid * 16 + m) * 128 + quad * 8;
        const u16* pc = wc1T + a * 16384 + (wid * 16 + m) * 128 + quad * 8;
        const u16* ph = h2T + a * 2048 + m * 128 + quad * 8;
#pragma unroll
        for (int ks = 0; ks < 4; ++ks) {
            wa[ks] = *(const short8*)(pa + ks * 32);
            wc[ks] = *(const short8*)(pc + ks * 32);
            h2f[ks] = *(const short8*)(ph + ks * 32);
        }
    }
    const float fa = ba1[a * 128 + wid * 16 + m];
    const float fc = bc1[a * 128 + wid * 16 + m];

    const u16* ysbase = ys_ws + ((size_t)a * 32768 + (size_t)blockIdx.x * 256 + srow) * 128 + schunk * 4;
    ushort4 pf = *(const ushort4*)(ysbase);

    for (int it = 0; it < 16; ++it) {
        *(ushort4*)&ysl[srow][schunk * 4] = pf;
        bar_lds();
        if (it + 1 < 16) pf = *(const ushort4*)(ysbase + (size_t)(it + 1) * 2048);

        short8 yf[4];
#pragma unroll
        for (int ks = 0; ks < 4; ++ks)
            yf[ks] = *(const short8*)&ysl[m][ks * 32 + quad * 8];
        f32x4 aa = f32x4{0.f, 0.f, 0.f, 0.f};
        f32x4 ac = f32x4{0.f, 0.f, 0.f, 0.f};
#pragma unroll
        for (int ks = 0; ks < 4; ++ks) {
            aa = mfma16(yf[ks], wa[ks], aa);
            ac = mfma16(yf[ks], wc[ks], ac);
        }
#pragma unroll
        for (int r = 0; r < 4; ++r) {
            al[0][quad * 4 + r][wid * 16 + m] = f2b(tanhf_(aa[r] + fa));
            al[1][quad * 4 + r][wid * 16 + m] = f2b(tanhf_(ac[r] + fc));
        }
        bar_lds();

        if (wid < 2) {
            short8 tf[4];
#pragma unroll
            for (int ks = 0; ks < 4; ++ks)
                tf[ks] = *(const short8*)&al[wid][m][ks * 32 + quad * 8];
            f32x4 tacc = f32x4{0.f, 0.f, 0.f, 0.f};
#pragma unroll
            for (int ks = 0; ks < 4; ++ks) tacc = mfma16(tf[ks], h2f[ks], tacc);
            const size_t R0 = (size_t)a * 32768 + (size_t)(blockIdx.x * 16 + it) * 16;
            if (wid == 0) {
                if (m < 8) {
                    const float bb = ba2[a * 8 + m];
#pragma unroll
                    for (int r = 0; r < 4; ++r)
                        mean_out[(R0 + quad * 4 + r) * 8 + m] = tacc[r] + bb;
                }
            } else {
                if (m == 8) {
                    const float bb = bc2[a];
#pragma unroll
                    for (int r = 0; r < 4; ++r)
                        val_out[R0 + quad * 4 + r] = tacc[r] + bb;
                }
            }
        }
    }
}

extern "C" void kernel_launch(void* const* d_in, const int* in_sizes, int n_in,
                              void* d_out, int out_size, void* d_ws, size_t ws_size,
                              hipStream_t stream) {
    const float* hstate = (const float*)d_in[0];
    const float* obs = (const float*)d_in[1];
    const float* We = (const float*)d_in[3];
    const float* be = (const float*)d_in[4];
    const float* Wi = (const float*)d_in[5];
    const float* bi = (const float*)d_in[6];
    const float* Wh = (const float*)d_in[7];
    const float* bhn = (const float*)d_in[8];
    const float* Wa1 = (const float*)d_in[9];
    const float* ba1 = (const float*)d_in[10];
    const float* Wa2 = (const float*)d_in[11];
    const float* ba2 = (const float*)d_in[12];
    const float* log_std = (const float*)d_in[13];
    const float* Wc1 = (const float*)d_in[14];
    const float* bc1 = (const float*)d_in[15];
    const float* Wc2 = (const float*)d_in[16];
    const float* bc2 = (const float*)d_in[17];
    const int* done = (const int*)d_in[18];

    float* out = (float*)d_out;
    float* hT_out = out;                    // (4,256,128)
    float* mean_out = out + 131072;         // (4,128,256,8)
    float* std_out = out + 1179648;         // (4,8)
    float* val_out = out + 1179680;         // (4,128,256)

    u16* ws = (u16*)d_ws;
    u16* xi = ws;
    u16* ys = xi + 50331648;
    u16* weT = ys + 16777216;
    u16* wiT = weT + 65536;
    u16* whT = wiT + 196608;
    u16* wa1T = whT + 196608;
    u16* wc1T = wa1T + 65536;
    u16* h2T = wc1T + 65536;

    hipLaunchKernelGGL(k_prep, dim3(2337), dim3(256), 0, stream,
                       We, Wi, Wh, Wa1, Wc1, Wa2, Wc2, log_std,
                       weT, wiT, whT, wa1T, wc1T, h2T, std_out);
    hipLaunchKernelGGL(k_embed_xi, dim3(128, 4), dim3(512), 0, stream,
                       obs, be, bi, weT, wiT, xi);
    hipLaunchKernelGGL(k_scan, dim3(16, 4), dim3(512), 0, stream,
                       hstate, xi, whT, bhn, done, ys, hT_out);
    hipLaunchKernelGGL(k_heads, dim3(128, 4), dim3(512), 0, stream,
                       ys, wa1T, wc1T, h2T, ba1, bc1, ba2, bc2, mean_out, val_out);
}